// Round 24
// baseline (210.035 us; speedup 1.0000x reference)
//
#include <hip/hip_runtime.h>

// Round 24: VPW 5->4, PGRID 2048->2500 for p2/p3 — 40000 = 2500x4x4 exactly
// (no idle waves, no tail; +22% waves for latency hiding; known trip count
// unrolls). Everything else identical to round 23.

#define BATCH 2
#define NPTS 100000
#define GNX 176
#define GNY 200
#define GNZ 10
#define NCELL (GNX*GNY*GNZ)
#define PMAX 32
#define MAXV 20000
#define NVOX (BATCH*MAXV)
#define NPFN (NVOX*PMAX)
#define CONVH 200
#define CONVW 176
#define NPIX (CONVH*CONVW)
#define NELEM (BATCH*NPIX*64)
#define SCAN_NB ((NCELL + 1023)/1024)
#define PGRID 2500
#define VPW 4
#define SHAD 8
#define WPB 720
#define KNEGINF 0x007FFFFFu    // monotone key of -inf; stored keys biased by -KNEGINF

typedef __attribute__((ext_vector_type(8))) short short8;
typedef __attribute__((ext_vector_type(4))) float f32x4;

__device__ __forceinline__ unsigned short f2bf(float f){
  unsigned int u = __float_as_uint(f);
  u = (u + 0x7fffu + ((u >> 16) & 1u)) >> 16;
  return (unsigned short)u;
}
__device__ __forceinline__ float bf2f(unsigned short s){
  return __uint_as_float(((unsigned int)s) << 16);
}
__device__ __forceinline__ float rdlane(float v, int lane){
  return __int_as_float(__builtin_amdgcn_readlane(__float_as_int(v), lane));
}

__device__ __forceinline__ int voxel_id(float x, float y, float z){
  int ix = (int)floorf(x / 0.4f);
  int iy = (int)floorf((y + 40.0f) / 0.4f);
  int iz = (int)floorf((z + 3.0f) / 0.4f);
  if (ix < 0 || iy < 0 || iz < 0 || ix >= GNX || iy >= GNY || iz >= GNZ) return -1;
  return (ix*GNY + iy)*GNZ + iz;
}

// k_init: blocks [0,WPB) prepack conv weights; blocks [WPB,grid) zero ws region
extern "C" __global__ void k_init(const float* __restrict__ cs_w, const float* __restrict__ rpn_w,
                                  unsigned short* __restrict__ Bw,
                                  uint4* __restrict__ zp, int n16){
  if (blockIdx.x < WPB){
    int i = blockIdx.x*256 + threadIdx.x;
    if (i >= 5*36864) return;
    int l = i/36864, r = i - l*36864;
    int tap = r >> 12, oc = (r >> 6) & 63, ic = r & 63;
    const float* src = (l < 2) ? (cs_w + (size_t)l*36864) : (rpn_w + (size_t)(l-2)*36864);
    Bw[i] = f2bf(src[((size_t)oc*64 + ic)*9 + tap]);
  } else {
    int i = (blockIdx.x - WPB)*256 + threadIdx.x;
    int stride = (gridDim.x - WPB)*256;
    uint4 z = make_uint4(0u,0u,0u,0u);
    for (; i < n16; i += stride) zp[i] = z;
  }
}

// 2 points per thread
extern "C" __global__ void k_count(const float* __restrict__ pts, int* __restrict__ cellcnt){
  int i = (blockIdx.x*256 + threadIdx.x)*2;
  if (i >= BATCH*NPTS) return;
  #pragma unroll
  for (int u=0;u<2;u++){
    int j = i + u;
    const float* q = pts + (size_t)j*4;
    int vid = voxel_id(q[0], q[1], q[2]);
    if (vid >= 0) atomicAdd(&cellcnt[(j/NPTS)*NCELL + vid], 1);
  }
}

extern "C" __global__ void __launch_bounds__(256) k_blkcount(const int* __restrict__ cellcnt,
                                                             int* __restrict__ blks){
  int b = blockIdx.y, blk = blockIdx.x, t = threadIdx.x;
  int base = blk*1024 + t*4;
  int s = 0;
  #pragma unroll
  for (int i=0;i<4;i++){ int c = base+i; if (c < NCELL) s += (cellcnt[b*NCELL+c] > 0); }
  #pragma unroll
  for (int m=32;m>=1;m>>=1) s += __shfl_xor(s, m);
  __shared__ int red[4];
  if ((t&63)==0) red[t>>6] = s;
  __syncthreads();
  if (t==0) blks[b*512+blk] = red[0]+red[1]+red[2]+red[3];
}

// k_assign: inline exclusive prefix over raw blks (k_scan folded in)
extern "C" __global__ void __launch_bounds__(256) k_assign(const int* __restrict__ cellcnt,
    const int* __restrict__ blks, int* __restrict__ slotmap, int* __restrict__ vv,
    int* __restrict__ cnt){
  int b = blockIdx.y, blk = blockIdx.x, t = threadIdx.x;
  __shared__ int pred[4];
  int pacc = 0;
  for (int i = t; i < blk; i += 256) pacc += blks[b*512 + i];
  #pragma unroll
  for (int m=32;m>=1;m>>=1) pacc += __shfl_xor(pacc, m);
  if ((t&63)==0) pred[t>>6] = pacc;
  __syncthreads();
  const int base0 = pred[0]+pred[1]+pred[2]+pred[3];
  int base = blk*1024 + t*4;
  int flag[4]; int s = 0;
  #pragma unroll
  for (int i=0;i<4;i++){
    int c = base+i;
    flag[i] = (c < NCELL) ? (cellcnt[b*NCELL+c] > 0) : 0;
    s += flag[i];
  }
  __shared__ int lds[256];
  lds[t] = s; __syncthreads();
  for (int o=1;o<256;o<<=1){
    int v = (t>=o) ? lds[t-o] : 0;
    __syncthreads();
    lds[t] += v;
    __syncthreads();
  }
  int run = base0 + (lds[t]-s);
  #pragma unroll
  for (int i=0;i<4;i++){
    int c = base+i;
    if (c >= NCELL) break;
    int sm = -1;
    if (flag[i]){
      if (run < MAXV){
        sm = run;
        vv[b*MAXV+run]  = c;
        cnt[b*MAXV+run] = min(cellcnt[b*NCELL+c], PMAX);
      }
      run++;
    }
    slotmap[b*NCELL+c] = sm;
  }
}

// 2 points per thread
extern "C" __global__ void k_fill(const float* __restrict__ pts, const int* __restrict__ slotmap,
                                  int* __restrict__ fill, int* __restrict__ plist){
  int i = (blockIdx.x*256 + threadIdx.x)*2;
  if (i >= BATCH*NPTS) return;
  #pragma unroll
  for (int u=0;u<2;u++){
    int j = i + u;
    const float* q = pts + (size_t)j*4;
    int vid = voxel_id(q[0], q[1], q[2]);
    if (vid < 0) continue;
    int b = j / NPTS;
    int slot = slotmap[b*NCELL+vid];
    if (slot < 0) continue;
    int pos = atomicAdd(&fill[b*MAXV+slot], 1);
    if (pos < PMAX) plist[((size_t)b*MAXV+slot)*PMAX + pos] = j - b*NPTS;
  }
}

// gather sorted points into pvox/mean + fold layer-1 stats; 32 voxels/block
extern "C" __global__ void __launch_bounds__(256) k_feat(const float* __restrict__ pts,
    const int* __restrict__ cnt, const int* __restrict__ plist, const float* __restrict__ w1,
    float* __restrict__ pvox, float* __restrict__ mean, float* __restrict__ st){
  __shared__ int lst[8][32];
  __shared__ float sred[64];
  int tid = threadIdx.x;
  if (tid < 64) sred[tid] = 0.f;
  int g = tid >> 5, p = tid & 31;
  float w1r[7];
  #pragma unroll
  for (int k=0;k<7;k++) w1r[k] = w1[k*32+p];
  float S = 0.f, Q = 0.f;
  for (int vb = 0; vb < 4; vb++){
    int fv = blockIdx.x*32 + vb*8 + g;
    int b  = fv / MAXV;
    int c  = cnt[fv];
    if (p < c) lst[g][p] = plist[(size_t)fv*PMAX + p];
    __syncthreads();
    if (p == 0){
      for (int i=1;i<c;i++){
        int key = lst[g][i]; int j = i-1;
        while (j >= 0 && lst[g][j] > key){ lst[g][j+1] = lst[g][j]; j--; }
        lst[g][j+1] = key;
      }
    }
    __syncthreads();
    float4 pt = make_float4(0.f,0.f,0.f,0.f);
    if (p < c) pt = *(const float4*)(pts + ((size_t)b*NPTS + lst[g][p])*4);
    float sx = pt.x, sy = pt.y, sz = pt.z;
    #pragma unroll
    for (int m=16;m>=1;m>>=1){
      sx += __shfl_xor(sx, m, 32); sy += __shfl_xor(sy, m, 32); sz += __shfl_xor(sz, m, 32);
    }
    float cd = (float)max(c, 1);
    float mx = sx/cd, my = sy/cd, mz = sz/cd;
    if (p < c) *(float4*)(pvox + ((size_t)fv*32 + p)*4) = pt;
    if (p == 0) *(float4*)(mean + (size_t)fv*4) = make_float4(mx, my, mz, 0.f);
    for (int q2 = 0; q2 < c; q2++){
      float px = __shfl(pt.x, q2, 32), py = __shfl(pt.y, q2, 32);
      float pz = __shfl(pt.z, q2, 32), pw = __shfl(pt.w, q2, 32);
      float in[7] = {px, py, pz, pw, px-mx, py-my, pz-mz};
      float v = 0.f;
      #pragma unroll
      for (int k=0;k<7;k++) v += in[k]*w1r[k];
      S += v; Q += v*v;
    }
    __syncthreads();
  }
  atomicAdd(&sred[p], S); atomicAdd(&sred[32+p], Q);
  __syncthreads();
  if (tid < 64) atomicAdd(&st[(blockIdx.x&(SHAD-1))*64 + tid], sred[tid]);
}

#define IN7(pt, mn) {pt.x, pt.y, pt.z, pt.w, pt.x-mn.x, pt.y-mn.y, pt.z-mn.z}

// p2: single point pass computes everything point-dependent; stores VL, K2.
extern "C" __global__ void __launch_bounds__(256) k_p2(const float* __restrict__ pvox,
    const float* __restrict__ mean, const int* __restrict__ cnt,
    const float* __restrict__ w1, const float* __restrict__ g1, const float* __restrict__ b1,
    const float* __restrict__ w2, const float* __restrict__ w3,
    const float* __restrict__ g2, const float* __restrict__ g3,
    const float* __restrict__ st1, float* __restrict__ st2, float* __restrict__ st3,
    float* __restrict__ K2buf, uint2* __restrict__ VL){
  __shared__ float w2KL[2048];   // float4 [j4(8)][lane]
  __shared__ float sred[256];
  int tid = threadIdx.x;
  for (int i = tid; i < 512; i += 256){
    int j4 = i >> 6, ln = i & 63;
    float4 v;
    v.x = w2[(7+j4*4+0)*64+ln];
    v.y = w2[(7+j4*4+1)*64+ln];
    v.z = w2[(7+j4*4+2)*64+ln];
    v.w = w2[(7+j4*4+3)*64+ln];
    ((float4*)w2KL)[i] = v;
  }
  sred[tid] = 0.f;
  int w = tid>>6, lane = tid&63, c1 = lane&31;
  float w1r[7], w2r[7], w3r[7];
  #pragma unroll
  for (int k=0;k<7;k++){ w1r[k] = w1[k*32+c1]; w2r[k] = w2[k*64+lane]; w3r[k] = w3[k*64+lane]; }
  const bool g2pos = (g2[lane] >= 0.f);
  const bool g3pos = (g3[lane] >= 0.f);
  const float invN = 1.f/(float)NPFN;
  float m1=0.f, v1s=0.f;
  #pragma unroll
  for (int s=0;s<SHAD;s++){ m1 += st1[s*64+c1]; v1s += st1[s*64+32+c1]; }
  m1 *= invN; v1s = v1s*invN - m1*m1;
  float sc1 = g1[c1]*rsqrtf(v1s + 1e-3f);
  float sh1 = b1[c1] - m1*sc1;
  __syncthreads();
  const float4* w2K4 = (const float4*)w2KL;
  const int wid = blockIdx.x*4 + w;
  int fv = wid*VPW;
  const int lim = min(fv + VPW, NVOX);
  int c_n = 0;
  float4 mn_n = make_float4(0.f,0.f,0.f,0.f), p0_n = mn_n, p1_n = mn_n;
  if (fv < lim){
    c_n  = cnt[fv];
    mn_n = *(const float4*)(mean + (size_t)fv*4);
    p0_n = *(const float4*)(pvox + ((size_t)fv*32+0)*4);
    p1_n = *(const float4*)(pvox + ((size_t)fv*32+1)*4);
  }
  float S = 0.f, Q = 0.f, S3 = 0.f, Q3 = 0.f;
  while (fv < lim){
    const int fvc = fv;
    const int c_ = c_n;
    const float4 mn = mn_n, p0 = p0_n, p1 = p1_n;
    fv += 1;
    if (fv < lim){
      c_n  = cnt[fv];
      mn_n = *(const float4*)(mean + (size_t)fv*4);
      p0_n = *(const float4*)(pvox + ((size_t)fv*32+0)*4);
      p1_n = *(const float4*)(pvox + ((size_t)fv*32+1)*4);
    }
    float vm = 0.f, sa = 0.f, sq = 0.f;
    float amx2 = -3.4e38f, amn2 = 3.4e38f;
    float sa3 = 0.f, sq3 = 0.f, amx3 = -3.4e38f, amn3 = 3.4e38f;
    {
      float in[7] = IN7(p0, mn);
      float v1 = 0.f, a2 = 0.f, a3 = 0.f;
      #pragma unroll
      for (int k=0;k<7;k++){ v1 += in[k]*w1r[k]; a2 += in[k]*w2r[k]; a3 += in[k]*w3r[k]; }
      if (c_ > 0){
        vm = fmaxf(vm, v1*sc1 + sh1);
        sa += a2; sq += a2*a2;
        amx2 = fmaxf(amx2, a2); amn2 = fminf(amn2, a2);
        sa3 += a3; sq3 += a3*a3;
        amx3 = fmaxf(amx3, a3); amn3 = fminf(amn3, a3);
      }
    }
    {
      float in[7] = IN7(p1, mn);
      float v1 = 0.f, a2 = 0.f, a3 = 0.f;
      #pragma unroll
      for (int k=0;k<7;k++){ v1 += in[k]*w1r[k]; a2 += in[k]*w2r[k]; a3 += in[k]*w3r[k]; }
      if (c_ > 1){
        vm = fmaxf(vm, v1*sc1 + sh1);
        sa += a2; sq += a2*a2;
        amx2 = fmaxf(amx2, a2); amn2 = fminf(amn2, a2);
        sa3 += a3; sq3 += a3*a3;
        amx3 = fmaxf(amx3, a3); amn3 = fminf(amn3, a3);
      }
    }
    for (int p = 2; p < c_; p++){
      float4 pt = *(const float4*)(pvox + ((size_t)fvc*32+p)*4);
      float in[7] = IN7(pt, mn);
      float v1 = 0.f, a2 = 0.f, a3 = 0.f;
      #pragma unroll
      for (int k=0;k<7;k++){ v1 += in[k]*w1r[k]; a2 += in[k]*w2r[k]; a3 += in[k]*w3r[k]; }
      vm = fmaxf(vm, v1*sc1 + sh1);
      sa += a2; sq += a2*a2;
      amx2 = fmaxf(amx2, a2); amn2 = fminf(amn2, a2);
      sa3 += a3; sq3 += a3*a3;
      amx3 = fmaxf(amx3, a3); amn3 = fminf(amn3, a3);
    }
    float k0=0.f,k1=0.f,k2=0.f,k3=0.f;
    #pragma unroll
    for (int j4=0;j4<8;j4++){
      float4 wv = w2K4[j4*64 + lane];
      k0 += rdlane(vm, 4*j4  )*wv.x;
      k1 += rdlane(vm, 4*j4+1)*wv.y;
      k2 += rdlane(vm, 4*j4+2)*wv.z;
      k3 += rdlane(vm, 4*j4+3)*wv.w;
    }
    float K = (k0+k1)+(k2+k3);
    if (c_){
      K2buf[(size_t)fvc*64 + lane] = K;
      float e2   = g2pos ? amx2 : amn2;
      float ext3 = g3pos ? amx3 : amn3;
      VL[(size_t)fvc*64 + lane] =
        make_uint2((unsigned)f2bf(e2) | ((unsigned)f2bf(ext3) << 16), __float_as_uint(sa3));
    }
    S  += (float)PMAX*K + sa;
    Q  += (float)PMAX*K*K + sq + 2.f*K*sa;
    S3 += sa3;
    Q3 += sq3;
  }
  atomicAdd(&sred[lane], S); atomicAdd(&sred[64+lane], Q);
  atomicAdd(&sred[128+lane], S3); atomicAdd(&sred[192+lane], Q3);
  __syncthreads();
  if (tid < 128) atomicAdd(&st2[(blockIdx.x&(SHAD-1))*128 + tid], sred[tid]);
  else           atomicAdd(&st3[(blockIdx.x&(SHAD-1))*128 + (tid-128)], sred[tid]);
}

// p3: loop-free per voxel — vm closed-form, K3 dot, scatter
extern "C" __global__ void __launch_bounds__(256) k_p3(const int* __restrict__ cnt,
    const int* __restrict__ vv, const float* __restrict__ g2, const float* __restrict__ b2,
    const float* __restrict__ w3, const float* __restrict__ g3,
    const float* __restrict__ st2, float* __restrict__ st3,
    const float* __restrict__ K2buf, const uint2* __restrict__ VL,
    unsigned* __restrict__ bev){
  __shared__ float w3KL[4096];    // float4 [j4(16)][lane]
  __shared__ float sred[128];
  int tid = threadIdx.x;
  for (int i = tid; i < 1024; i += 256){
    int j4 = i >> 6, ln = i & 63;
    float4 v;
    v.x = w3[(7+j4*4+0)*64+ln];
    v.y = w3[(7+j4*4+1)*64+ln];
    v.z = w3[(7+j4*4+2)*64+ln];
    v.w = w3[(7+j4*4+3)*64+ln];
    ((float4*)w3KL)[i] = v;
  }
  if (tid < 128) sred[tid] = 0.f;
  int w = tid>>6, lane = tid&63;
  const float invN = 1.f/(float)NPFN;
  float m2=0.f, v2s=0.f;
  #pragma unroll
  for (int s=0;s<SHAD;s++){ m2 += st2[s*128+lane]; v2s += st2[s*128+64+lane]; }
  m2 *= invN; v2s = v2s*invN - m2*m2;
  float sc2 = g2[lane]*rsqrtf(v2s + 1e-3f);
  float sh2 = b2[lane] - m2*sc2;
  bool pickmax = (g3[lane] >= 0.f);
  __syncthreads();
  const float4* w3K4 = (const float4*)w3KL;
  const int wid = blockIdx.x*4 + w;
  int fv = wid*VPW;
  const int lim = min(fv + VPW, NVOX);
  int c_n = 0, vv_n = 0; float K2_n = 0.f;
  uint2 vl_n = make_uint2(0u,0u);
  if (fv < lim){
    c_n  = cnt[fv];
    vv_n = vv[fv];
    K2_n = K2buf[(size_t)fv*64 + lane];
    vl_n = VL[(size_t)fv*64 + lane];
  }
  float S = 0.f, Q = 0.f;
  while (fv < lim){
    const int fvc = fv;
    const int c_ = c_n, vid = vv_n;
    const float K2 = K2_n;
    const uint2 vl = vl_n;
    fv += 1;
    if (fv < lim){
      c_n  = cnt[fv];
      vv_n = vv[fv];
      K2_n = K2buf[(size_t)fv*64 + lane];
      vl_n = VL[(size_t)fv*64 + lane];
    }
    float e2   = bf2f((unsigned short)(vl.x & 0xffffu));
    float ext3 = bf2f((unsigned short)(vl.x >> 16));
    float sa3  = __uint_as_float(vl.y);
    float vm = (c_ > 0) ? fmaxf(0.f, (e2 + K2)*sc2 + sh2) : 0.f;
    float k0=0.f,k1=0.f,k2=0.f,k3=0.f;
    #pragma unroll
    for (int j4=0;j4<16;j4++){
      float4 wv = w3K4[j4*64 + lane];
      k0 += rdlane(vm, 4*j4  )*wv.x;
      k1 += rdlane(vm, 4*j4+1)*wv.y;
      k2 += rdlane(vm, 4*j4+2)*wv.z;
      k3 += rdlane(vm, 4*j4+3)*wv.w;
    }
    float K3 = (k0+k1)+(k2+k3);
    if (c_){
      float raw = ext3 + K3;
      if (!pickmax) raw = -raw;
      unsigned u = __float_as_uint(raw);
      unsigned key = (u & 0x80000000u) ? ~u : (u | 0x80000000u);
      int bb = fvc / MAXV;
      int cx = vid / (GNY*GNZ);
      int cy = (vid / GNZ) % GNY;
      atomicMax(bev + (((size_t)bb*NPIX + (size_t)cy*CONVW + cx)*64) + lane,
                key - KNEGINF);
    }
    S += (float)PMAX*K3;
    Q += (float)PMAX*K3*K3 + (c_ ? 2.f*K3*sa3 : 0.f);
  }
  atomicAdd(&sred[lane], S); atomicAdd(&sred[64+lane], Q);
  __syncthreads();
  if (tid < 128) atomicAdd(&st3[(blockIdx.x&(SHAD-1))*128 + tid], sred[tid]);
}

// ---- conv3x3: implicit GEMM, bf16 MFMA, tile 16x20 (exact fit, no y-guard)
#define CTH 20
extern "C" __global__ void __launch_bounds__(256) k_conv(const unsigned* __restrict__ inK,
    const unsigned short* __restrict__ inH,
    const float* __restrict__ stin, const float* __restrict__ g, const float* __restrict__ be,
    float eps, float invN, int raw0,
    const unsigned short* __restrict__ Bw, const float* __restrict__ bias,
    unsigned short* __restrict__ out, float* __restrict__ st){
  const int b  = blockIdx.z;
  const int x0 = blockIdx.x*16, y0 = blockIdx.y*CTH;
  const int tid = threadIdx.x;
  const int w = tid >> 6, l = tid & 63;
  const int l15 = l & 15, quad = l >> 4;
  const int bid = (blockIdx.z*gridDim.y + blockIdx.y)*gridDim.x + blockIdx.x;
  const int shad = bid & (SHAD-1);

  __shared__ unsigned short smemA[(CTH+2)*18*64];   // 50688 B
  __shared__ float bnsc[64], bnsh[64];
  __shared__ float sA[64], sQ[64];
  if (tid < 64){
    sA[tid] = 0.f; sQ[tid] = 0.f;
    float m = 0.f, q = 0.f;
    #pragma unroll
    for (int s=0;s<SHAD;s++){ m += stin[s*128+tid]; q += stin[s*128+64+tid]; }
    m *= invN;
    float va = q*invN - m*m;
    float sc = g[tid]*rsqrtf(va + eps);
    bnsc[tid] = sc; bnsh[tid] = be[tid] - m*sc;
  }
  __syncthreads();

  for (int i = tid; i < (CTH+2)*18*8; i += 256){
    int pos = i >> 3, jb = i & 7;
    int yp = pos/18, xp = pos - yp*18;
    int gy = y0 + yp - 1, gx = x0 + xp - 1;
    unsigned short h[8] = {0,0,0,0,0,0,0,0};
    if (gy >= 0 && gy < CONVH && gx >= 0 && gx < CONVW){
      size_t ebase = ((size_t)b*NPIX + (size_t)gy*CONVW + gx)*64 + jb*8;
      float f[8];
      if (raw0){
        uint4 u0 = *(const uint4*)(inK + ebase);
        uint4 u1 = *(const uint4*)(inK + ebase + 4);
        unsigned kk[8] = {u0.x,u0.y,u0.z,u0.w,u1.x,u1.y,u1.z,u1.w};
        #pragma unroll
        for (int k=0;k<8;k++){
          unsigned key = kk[k] + KNEGINF;
          unsigned u = (key & 0x80000000u) ? (key & 0x7fffffffu) : ~key;
          float v = __uint_as_float(u);
          int c = jb*8 + k;
          if (bnsc[c] < 0.f) v = -v;
          f[k] = v;
        }
      } else {
        uint4 v4 = *(const uint4*)(inH + ebase);
        unsigned uu[4] = {v4.x, v4.y, v4.z, v4.w};
        #pragma unroll
        for (int e=0;e<4;e++){
          f[e*2]   = bf2f((unsigned short)(uu[e] & 0xffffu));
          f[e*2+1] = bf2f((unsigned short)(uu[e] >> 16));
        }
      }
      #pragma unroll
      for (int k=0;k<8;k++){
        int c = jb*8 + k;
        h[k] = f2bf(fmaxf(f[k]*bnsc[c] + bnsh[c], 0.f));
      }
    }
    int jsw = jb ^ (xp & 7);
    *(uint4*)&smemA[pos*64 + jsw*8] = *(uint4*)h;
  }
  __syncthreads();

  f32x4 acc[5][4];
  #pragma unroll
  for (int rr=0;rr<5;rr++)
    #pragma unroll
    for (int nt=0;nt<4;nt++) acc[rr][nt] = (f32x4){0.f,0.f,0.f,0.f};
  #pragma unroll
  for (int tap = 0; tap < 9; tap++){
    const int dy = tap/3, dx = tap - dy*3;
    const int xp = l15 + dx;
    const int xm = xp & 7;
    short8 b0[4], b1[4];
    #pragma unroll
    for (int nt = 0; nt < 4; nt++){
      const unsigned short* bp = Bw + (((size_t)tap*64 + nt*16 + l15)*64 + quad*8);
      b0[nt] = *(const short8*)bp;
      b1[nt] = *(const short8*)(bp + 32);
    }
    #pragma unroll
    for (int rr = 0; rr < 5; rr++){
      int yp = 5*w + rr + dy;
      int abase = (yp*18 + xp)*64;
      short8 aL = *(const short8*)&smemA[abase + ((quad    ) ^ xm)*8];
      short8 aH = *(const short8*)&smemA[abase + ((4 + quad) ^ xm)*8];
      #pragma unroll
      for (int nt = 0; nt < 4; nt++)
        acc[rr][nt] = __builtin_amdgcn_mfma_f32_16x16x32_bf16(aL, b0[nt], acc[rr][nt], 0,0,0);
      #pragma unroll
      for (int nt = 0; nt < 4; nt++)
        acc[rr][nt] = __builtin_amdgcn_mfma_f32_16x16x32_bf16(aH, b1[nt], acc[rr][nt], 0,0,0);
    }
  }

  #pragma unroll
  for (int nt = 0; nt < 4; nt++){
    int oc = nt*16 + l15;
    float bv = bias[oc];
    float s = 0.f, q = 0.f;
    #pragma unroll
    for (int rr = 0; rr < 5; rr++){
      int y = y0 + 5*w + rr;
      size_t rbase = ((size_t)b*NPIX + (size_t)y*CONVW)*64;
      #pragma unroll
      for (int r = 0; r < 4; r++){
        float v = acc[rr][nt][r] + bv;
        int x = x0 + quad*4 + r;
        out[rbase + (size_t)x*64 + oc] = f2bf(v);
        s += v; q += v*v;
      }
    }
    s += __shfl_xor(s, 16); s += __shfl_xor(s, 32);
    q += __shfl_xor(q, 16); q += __shfl_xor(q, 32);
    if (quad == 0){ atomicAdd(&sA[oc], s); atomicAdd(&sQ[oc], q); }
  }
  __syncthreads();
  if (tid < 64){
    atomicAdd(&st[shad*128 + tid], sA[tid]);
    atomicAdd(&st[shad*128 + 64 + tid], sQ[tid]);
  }
}

// ---- head 1x1: bf16 in + fused BN/relu of last conv layer
extern "C" __global__ void __launch_bounds__(256) k_head(const unsigned short* __restrict__ in,
    const float* __restrict__ stin, const float* __restrict__ g, const float* __restrict__ be,
    const float* __restrict__ hw, const float* __restrict__ hb, float* __restrict__ outp){
  __shared__ float bnsc[64], bnsh[64];
  int tid = threadIdx.x;
  if (tid < 64){
    const float invN = 1.f/(float)(BATCH*NPIX);
    float m = 0.f, q = 0.f;
    #pragma unroll
    for (int s=0;s<SHAD;s++){ m += stin[s*128+tid]; q += stin[s*128+64+tid]; }
    m *= invN;
    float va = q*invN - m*m;
    float sc = g[tid]*rsqrtf(va + 1e-5f);
    bnsc[tid] = sc; bnsh[tid] = be[tid] - m*sc;
  }
  __syncthreads();
  int i = blockIdx.x*256 + tid;
  if (i >= BATCH*NPIX) return;
  const uint4* p = (const uint4*)(in + (size_t)i*64);
  float a0 = hb[0], a1 = hb[1], a2 = hb[2];
  #pragma unroll
  for (int jb = 0; jb < 8; jb++){
    uint4 u = p[jb];
    unsigned uu[4] = {u.x, u.y, u.z, u.w};
    #pragma unroll
    for (int e = 0; e < 4; e++){
      int ic = jb*8 + e*2;
      float v0 = bf2f((unsigned short)(uu[e] & 0xffffu));
      float v1 = bf2f((unsigned short)(uu[e] >> 16));
      float h0 = fmaxf(v0*bnsc[ic]   + bnsh[ic],   0.f);
      float h1 = fmaxf(v1*bnsc[ic+1] + bnsh[ic+1], 0.f);
      a0 += h0*hw[ic] + h1*hw[ic+1];
      a1 += h0*hw[64+ic] + h1*hw[64+ic+1];
      a2 += h0*hw[128+ic] + h1*hw[128+ic+1];
    }
  }
  size_t o = (size_t)i*3;
  outp[o+0] = a0; outp[o+1] = a1; outp[o+2] = a2;
}

extern "C" void kernel_launch(void* const* d_in, const int* in_sizes, int n_in,
                              void* d_out, int out_size, void* d_ws, size_t ws_size,
                              hipStream_t stream){
  (void)in_sizes; (void)n_in; (void)out_size;
  const float* pts   = (const float*)d_in[0];
  const float* w1    = (const float*)d_in[1];
  const float* g1    = (const float*)d_in[2];
  const float* b1    = (const float*)d_in[3];
  const float* w2    = (const float*)d_in[4];
  const float* g2    = (const float*)d_in[5];
  const float* b2    = (const float*)d_in[6];
  const float* w3    = (const float*)d_in[7];
  const float* g3    = (const float*)d_in[8];
  const float* b3    = (const float*)d_in[9];
  const float* cs_w  = (const float*)d_in[10];
  const float* cs_b  = (const float*)d_in[11];
  const float* cs_g  = (const float*)d_in[12];
  const float* cs_be = (const float*)d_in[13];
  const float* rpn_w = (const float*)d_in[14];
  const float* rpn_b = (const float*)d_in[15];
  const float* rpn_g = (const float*)d_in[16];
  const float* rpn_be= (const float*)d_in[17];
  const float* hw    = (const float*)d_in[18];
  const float* hb    = (const float*)d_in[19];

  char* ws = (char*)d_ws;
  size_t off = 0;
  auto alloc = [&](size_t bytes)->char*{
    char* p = ws + off; off += (bytes + 255) & ~(size_t)255; return p;
  };
  // ---- zero region (k_init) ----
  int*   cellcnt = (int*)  alloc((size_t)BATCH*NCELL*4);
  int*   vv      = (int*)  alloc((size_t)NVOX*4);
  int*   cnt     = (int*)  alloc((size_t)NVOX*4);
  int*   fill    = (int*)  alloc((size_t)NVOX*4);
  float* stats   = (float*)alloc(131072);
  unsigned* bevk = (unsigned*)alloc((size_t)NELEM*4);       // biased keys: 0 == -inf
  size_t zbytes  = off;
  // ---- no-init region ----
  int*   slotmap = (int*)  alloc((size_t)BATCH*NCELL*4);
  int*   blks    = (int*)  alloc((size_t)BATCH*512*4);
  int*   plist   = (int*)  alloc((size_t)NVOX*PMAX*4);      // conv alias start
  float* pvox    = (float*)alloc((size_t)NVOX*PMAX*16);
  float* mean    = (float*)alloc((size_t)NVOX*16);
  float* K2buf   = (float*)alloc((size_t)NVOX*64*4);
  uint2* VLbuf   = (uint2*)alloc((size_t)NVOX*64*8);
  unsigned short* Bw = (unsigned short*)alloc((size_t)5*36864*2);
  if (off > ws_size) return;

  float* st1 = stats;            // [8][64]
  float* st2 = stats + 512;      // [8][128]
  float* st3 = stats + 1536;     // [8][128]
  float* stc = stats + 2560;     // 5 x [8][128]

  unsigned short* convA = (unsigned short*)plist;
  unsigned short* convB = (unsigned short*)((char*)plist + 9011200);

  k_init<<<2048, 256, 0, stream>>>(cs_w, rpn_w, Bw, (uint4*)ws, (int)(zbytes/16));

  k_count <<<(BATCH*NPTS/2+255)/256, 256, 0, stream>>>(pts, cellcnt);
  k_blkcount<<<dim3(SCAN_NB,BATCH), 256, 0, stream>>>(cellcnt, blks);
  k_assign<<<dim3(SCAN_NB,BATCH), 256, 0, stream>>>(cellcnt, blks, slotmap, vv, cnt);
  k_fill  <<<(BATCH*NPTS/2+255)/256, 256, 0, stream>>>(pts, slotmap, fill, plist);
  k_feat  <<<NVOX/32, 256, 0, stream>>>(pts, cnt, plist, w1, pvox, mean, st1);

  k_p2<<<PGRID, 256, 0, stream>>>(pvox, mean, cnt, w1, g1, b1, w2, w3, g2, g3,
                                  st1, st2, st3, K2buf, VLbuf);
  k_p3<<<PGRID, 256, 0, stream>>>(cnt, vv, g2, b2, w3, g3, st2, st3,
                                  K2buf, VLbuf, bevk);

  const float* bptr[5]  = {cs_b, cs_b+64,   rpn_b, rpn_b+64,   rpn_b+128};
  const float* gptr[5]  = {cs_g, cs_g+64,   rpn_g, rpn_g+64,   rpn_g+128};
  const float* beptr[5] = {cs_be,cs_be+64,  rpn_be,rpn_be+64,  rpn_be+128};
  const unsigned short* srcs[5] = {nullptr, convA, convB, convA, convB};
  unsigned short*       dsts[5] = {convA, convB, convA, convB, convA};
  dim3 cgrid(CONVW/16, CONVH/CTH, BATCH);
  for (int ll = 0; ll < 5; ll++){
    const float* stin = (ll == 0) ? st3 : (stc + (ll-1)*1024);
    const float* gg   = (ll == 0) ? g3 : gptr[ll-1];
    const float* bb   = (ll == 0) ? b3 : beptr[ll-1];
    float eps  = (ll == 0) ? 1e-3f : 1e-5f;
    float invN = (ll == 0) ? 1.f/(float)NPFN : 1.f/(float)(BATCH*NPIX);
    k_conv<<<cgrid, 256, 0, stream>>>((ll==0)?bevk:nullptr, srcs[ll],
                                      stin, gg, bb, eps, invN, (ll==0)?1:0,
                                      Bw + (size_t)ll*36864, bptr[ll], dsts[ll],
                                      stc + ll*1024);
  }
  k_head<<<(BATCH*NPIX+255)/256, 256, 0, stream>>>(convA, stc + 4*1024, gptr[4], beptr[4],
                                                   hw, hb, (float*)d_out);
}

// Round 25
// 207.049 us; speedup vs baseline: 1.0144x; 1.0144x over previous
//
#include <hip/hip_runtime.h>

// Round 25: pure revert to round-23 measured best (VPW=5, PGRID=2048) —
// round-24's VPW4/PGRID2500 was -2.4us (prologue cost > TLP gain, same
// lesson as rounds 11/19). Everything else identical to round 23.

#define BATCH 2
#define NPTS 100000
#define GNX 176
#define GNY 200
#define GNZ 10
#define NCELL (GNX*GNY*GNZ)
#define PMAX 32
#define MAXV 20000
#define NVOX (BATCH*MAXV)
#define NPFN (NVOX*PMAX)
#define CONVH 200
#define CONVW 176
#define NPIX (CONVH*CONVW)
#define NELEM (BATCH*NPIX*64)
#define SCAN_NB ((NCELL + 1023)/1024)
#define PGRID 2048
#define VPW 5
#define SHAD 8
#define WPB 720
#define KNEGINF 0x007FFFFFu    // monotone key of -inf; stored keys biased by -KNEGINF

typedef __attribute__((ext_vector_type(8))) short short8;
typedef __attribute__((ext_vector_type(4))) float f32x4;

__device__ __forceinline__ unsigned short f2bf(float f){
  unsigned int u = __float_as_uint(f);
  u = (u + 0x7fffu + ((u >> 16) & 1u)) >> 16;
  return (unsigned short)u;
}
__device__ __forceinline__ float bf2f(unsigned short s){
  return __uint_as_float(((unsigned int)s) << 16);
}
__device__ __forceinline__ float rdlane(float v, int lane){
  return __int_as_float(__builtin_amdgcn_readlane(__float_as_int(v), lane));
}

__device__ __forceinline__ int voxel_id(float x, float y, float z){
  int ix = (int)floorf(x / 0.4f);
  int iy = (int)floorf((y + 40.0f) / 0.4f);
  int iz = (int)floorf((z + 3.0f) / 0.4f);
  if (ix < 0 || iy < 0 || iz < 0 || ix >= GNX || iy >= GNY || iz >= GNZ) return -1;
  return (ix*GNY + iy)*GNZ + iz;
}

// k_init: blocks [0,WPB) prepack conv weights; blocks [WPB,grid) zero ws region
extern "C" __global__ void k_init(const float* __restrict__ cs_w, const float* __restrict__ rpn_w,
                                  unsigned short* __restrict__ Bw,
                                  uint4* __restrict__ zp, int n16){
  if (blockIdx.x < WPB){
    int i = blockIdx.x*256 + threadIdx.x;
    if (i >= 5*36864) return;
    int l = i/36864, r = i - l*36864;
    int tap = r >> 12, oc = (r >> 6) & 63, ic = r & 63;
    const float* src = (l < 2) ? (cs_w + (size_t)l*36864) : (rpn_w + (size_t)(l-2)*36864);
    Bw[i] = f2bf(src[((size_t)oc*64 + ic)*9 + tap]);
  } else {
    int i = (blockIdx.x - WPB)*256 + threadIdx.x;
    int stride = (gridDim.x - WPB)*256;
    uint4 z = make_uint4(0u,0u,0u,0u);
    for (; i < n16; i += stride) zp[i] = z;
  }
}

// 2 points per thread
extern "C" __global__ void k_count(const float* __restrict__ pts, int* __restrict__ cellcnt){
  int i = (blockIdx.x*256 + threadIdx.x)*2;
  if (i >= BATCH*NPTS) return;
  #pragma unroll
  for (int u=0;u<2;u++){
    int j = i + u;
    const float* q = pts + (size_t)j*4;
    int vid = voxel_id(q[0], q[1], q[2]);
    if (vid >= 0) atomicAdd(&cellcnt[(j/NPTS)*NCELL + vid], 1);
  }
}

extern "C" __global__ void __launch_bounds__(256) k_blkcount(const int* __restrict__ cellcnt,
                                                             int* __restrict__ blks){
  int b = blockIdx.y, blk = blockIdx.x, t = threadIdx.x;
  int base = blk*1024 + t*4;
  int s = 0;
  #pragma unroll
  for (int i=0;i<4;i++){ int c = base+i; if (c < NCELL) s += (cellcnt[b*NCELL+c] > 0); }
  #pragma unroll
  for (int m=32;m>=1;m>>=1) s += __shfl_xor(s, m);
  __shared__ int red[4];
  if ((t&63)==0) red[t>>6] = s;
  __syncthreads();
  if (t==0) blks[b*512+blk] = red[0]+red[1]+red[2]+red[3];
}

// k_assign: inline exclusive prefix over raw blks (k_scan folded in)
extern "C" __global__ void __launch_bounds__(256) k_assign(const int* __restrict__ cellcnt,
    const int* __restrict__ blks, int* __restrict__ slotmap, int* __restrict__ vv,
    int* __restrict__ cnt){
  int b = blockIdx.y, blk = blockIdx.x, t = threadIdx.x;
  __shared__ int pred[4];
  int pacc = 0;
  for (int i = t; i < blk; i += 256) pacc += blks[b*512 + i];
  #pragma unroll
  for (int m=32;m>=1;m>>=1) pacc += __shfl_xor(pacc, m);
  if ((t&63)==0) pred[t>>6] = pacc;
  __syncthreads();
  const int base0 = pred[0]+pred[1]+pred[2]+pred[3];
  int base = blk*1024 + t*4;
  int flag[4]; int s = 0;
  #pragma unroll
  for (int i=0;i<4;i++){
    int c = base+i;
    flag[i] = (c < NCELL) ? (cellcnt[b*NCELL+c] > 0) : 0;
    s += flag[i];
  }
  __shared__ int lds[256];
  lds[t] = s; __syncthreads();
  for (int o=1;o<256;o<<=1){
    int v = (t>=o) ? lds[t-o] : 0;
    __syncthreads();
    lds[t] += v;
    __syncthreads();
  }
  int run = base0 + (lds[t]-s);
  #pragma unroll
  for (int i=0;i<4;i++){
    int c = base+i;
    if (c >= NCELL) break;
    int sm = -1;
    if (flag[i]){
      if (run < MAXV){
        sm = run;
        vv[b*MAXV+run]  = c;
        cnt[b*MAXV+run] = min(cellcnt[b*NCELL+c], PMAX);
      }
      run++;
    }
    slotmap[b*NCELL+c] = sm;
  }
}

// 2 points per thread
extern "C" __global__ void k_fill(const float* __restrict__ pts, const int* __restrict__ slotmap,
                                  int* __restrict__ fill, int* __restrict__ plist){
  int i = (blockIdx.x*256 + threadIdx.x)*2;
  if (i >= BATCH*NPTS) return;
  #pragma unroll
  for (int u=0;u<2;u++){
    int j = i + u;
    const float* q = pts + (size_t)j*4;
    int vid = voxel_id(q[0], q[1], q[2]);
    if (vid < 0) continue;
    int b = j / NPTS;
    int slot = slotmap[b*NCELL+vid];
    if (slot < 0) continue;
    int pos = atomicAdd(&fill[b*MAXV+slot], 1);
    if (pos < PMAX) plist[((size_t)b*MAXV+slot)*PMAX + pos] = j - b*NPTS;
  }
}

// gather sorted points into pvox/mean + fold layer-1 stats; 32 voxels/block
extern "C" __global__ void __launch_bounds__(256) k_feat(const float* __restrict__ pts,
    const int* __restrict__ cnt, const int* __restrict__ plist, const float* __restrict__ w1,
    float* __restrict__ pvox, float* __restrict__ mean, float* __restrict__ st){
  __shared__ int lst[8][32];
  __shared__ float sred[64];
  int tid = threadIdx.x;
  if (tid < 64) sred[tid] = 0.f;
  int g = tid >> 5, p = tid & 31;
  float w1r[7];
  #pragma unroll
  for (int k=0;k<7;k++) w1r[k] = w1[k*32+p];
  float S = 0.f, Q = 0.f;
  for (int vb = 0; vb < 4; vb++){
    int fv = blockIdx.x*32 + vb*8 + g;
    int b  = fv / MAXV;
    int c  = cnt[fv];
    if (p < c) lst[g][p] = plist[(size_t)fv*PMAX + p];
    __syncthreads();
    if (p == 0){
      for (int i=1;i<c;i++){
        int key = lst[g][i]; int j = i-1;
        while (j >= 0 && lst[g][j] > key){ lst[g][j+1] = lst[g][j]; j--; }
        lst[g][j+1] = key;
      }
    }
    __syncthreads();
    float4 pt = make_float4(0.f,0.f,0.f,0.f);
    if (p < c) pt = *(const float4*)(pts + ((size_t)b*NPTS + lst[g][p])*4);
    float sx = pt.x, sy = pt.y, sz = pt.z;
    #pragma unroll
    for (int m=16;m>=1;m>>=1){
      sx += __shfl_xor(sx, m, 32); sy += __shfl_xor(sy, m, 32); sz += __shfl_xor(sz, m, 32);
    }
    float cd = (float)max(c, 1);
    float mx = sx/cd, my = sy/cd, mz = sz/cd;
    if (p < c) *(float4*)(pvox + ((size_t)fv*32 + p)*4) = pt;
    if (p == 0) *(float4*)(mean + (size_t)fv*4) = make_float4(mx, my, mz, 0.f);
    for (int q2 = 0; q2 < c; q2++){
      float px = __shfl(pt.x, q2, 32), py = __shfl(pt.y, q2, 32);
      float pz = __shfl(pt.z, q2, 32), pw = __shfl(pt.w, q2, 32);
      float in[7] = {px, py, pz, pw, px-mx, py-my, pz-mz};
      float v = 0.f;
      #pragma unroll
      for (int k=0;k<7;k++) v += in[k]*w1r[k];
      S += v; Q += v*v;
    }
    __syncthreads();
  }
  atomicAdd(&sred[p], S); atomicAdd(&sred[32+p], Q);
  __syncthreads();
  if (tid < 64) atomicAdd(&st[(blockIdx.x&(SHAD-1))*64 + tid], sred[tid]);
}

#define IN7(pt, mn) {pt.x, pt.y, pt.z, pt.w, pt.x-mn.x, pt.y-mn.y, pt.z-mn.z}

// p2: single point pass computes everything point-dependent; stores VL, K2.
extern "C" __global__ void __launch_bounds__(256) k_p2(const float* __restrict__ pvox,
    const float* __restrict__ mean, const int* __restrict__ cnt,
    const float* __restrict__ w1, const float* __restrict__ g1, const float* __restrict__ b1,
    const float* __restrict__ w2, const float* __restrict__ w3,
    const float* __restrict__ g2, const float* __restrict__ g3,
    const float* __restrict__ st1, float* __restrict__ st2, float* __restrict__ st3,
    float* __restrict__ K2buf, uint2* __restrict__ VL){
  __shared__ float w2KL[2048];   // float4 [j4(8)][lane]
  __shared__ float sred[256];
  int tid = threadIdx.x;
  for (int i = tid; i < 512; i += 256){
    int j4 = i >> 6, ln = i & 63;
    float4 v;
    v.x = w2[(7+j4*4+0)*64+ln];
    v.y = w2[(7+j4*4+1)*64+ln];
    v.z = w2[(7+j4*4+2)*64+ln];
    v.w = w2[(7+j4*4+3)*64+ln];
    ((float4*)w2KL)[i] = v;
  }
  sred[tid] = 0.f;
  int w = tid>>6, lane = tid&63, c1 = lane&31;
  float w1r[7], w2r[7], w3r[7];
  #pragma unroll
  for (int k=0;k<7;k++){ w1r[k] = w1[k*32+c1]; w2r[k] = w2[k*64+lane]; w3r[k] = w3[k*64+lane]; }
  const bool g2pos = (g2[lane] >= 0.f);
  const bool g3pos = (g3[lane] >= 0.f);
  const float invN = 1.f/(float)NPFN;
  float m1=0.f, v1s=0.f;
  #pragma unroll
  for (int s=0;s<SHAD;s++){ m1 += st1[s*64+c1]; v1s += st1[s*64+32+c1]; }
  m1 *= invN; v1s = v1s*invN - m1*m1;
  float sc1 = g1[c1]*rsqrtf(v1s + 1e-3f);
  float sh1 = b1[c1] - m1*sc1;
  __syncthreads();
  const float4* w2K4 = (const float4*)w2KL;
  const int wid = blockIdx.x*4 + w;
  int fv = wid*VPW;
  const int lim = min(fv + VPW, NVOX);
  int c_n = 0;
  float4 mn_n = make_float4(0.f,0.f,0.f,0.f), p0_n = mn_n, p1_n = mn_n;
  if (fv < lim){
    c_n  = cnt[fv];
    mn_n = *(const float4*)(mean + (size_t)fv*4);
    p0_n = *(const float4*)(pvox + ((size_t)fv*32+0)*4);
    p1_n = *(const float4*)(pvox + ((size_t)fv*32+1)*4);
  }
  float S = 0.f, Q = 0.f, S3 = 0.f, Q3 = 0.f;
  while (fv < lim){
    const int fvc = fv;
    const int c_ = c_n;
    const float4 mn = mn_n, p0 = p0_n, p1 = p1_n;
    fv += 1;
    if (fv < lim){
      c_n  = cnt[fv];
      mn_n = *(const float4*)(mean + (size_t)fv*4);
      p0_n = *(const float4*)(pvox + ((size_t)fv*32+0)*4);
      p1_n = *(const float4*)(pvox + ((size_t)fv*32+1)*4);
    }
    float vm = 0.f, sa = 0.f, sq = 0.f;
    float amx2 = -3.4e38f, amn2 = 3.4e38f;
    float sa3 = 0.f, sq3 = 0.f, amx3 = -3.4e38f, amn3 = 3.4e38f;
    {
      float in[7] = IN7(p0, mn);
      float v1 = 0.f, a2 = 0.f, a3 = 0.f;
      #pragma unroll
      for (int k=0;k<7;k++){ v1 += in[k]*w1r[k]; a2 += in[k]*w2r[k]; a3 += in[k]*w3r[k]; }
      if (c_ > 0){
        vm = fmaxf(vm, v1*sc1 + sh1);
        sa += a2; sq += a2*a2;
        amx2 = fmaxf(amx2, a2); amn2 = fminf(amn2, a2);
        sa3 += a3; sq3 += a3*a3;
        amx3 = fmaxf(amx3, a3); amn3 = fminf(amn3, a3);
      }
    }
    {
      float in[7] = IN7(p1, mn);
      float v1 = 0.f, a2 = 0.f, a3 = 0.f;
      #pragma unroll
      for (int k=0;k<7;k++){ v1 += in[k]*w1r[k]; a2 += in[k]*w2r[k]; a3 += in[k]*w3r[k]; }
      if (c_ > 1){
        vm = fmaxf(vm, v1*sc1 + sh1);
        sa += a2; sq += a2*a2;
        amx2 = fmaxf(amx2, a2); amn2 = fminf(amn2, a2);
        sa3 += a3; sq3 += a3*a3;
        amx3 = fmaxf(amx3, a3); amn3 = fminf(amn3, a3);
      }
    }
    for (int p = 2; p < c_; p++){
      float4 pt = *(const float4*)(pvox + ((size_t)fvc*32+p)*4);
      float in[7] = IN7(pt, mn);
      float v1 = 0.f, a2 = 0.f, a3 = 0.f;
      #pragma unroll
      for (int k=0;k<7;k++){ v1 += in[k]*w1r[k]; a2 += in[k]*w2r[k]; a3 += in[k]*w3r[k]; }
      vm = fmaxf(vm, v1*sc1 + sh1);
      sa += a2; sq += a2*a2;
      amx2 = fmaxf(amx2, a2); amn2 = fminf(amn2, a2);
      sa3 += a3; sq3 += a3*a3;
      amx3 = fmaxf(amx3, a3); amn3 = fminf(amn3, a3);
    }
    float k0=0.f,k1=0.f,k2=0.f,k3=0.f;
    #pragma unroll
    for (int j4=0;j4<8;j4++){
      float4 wv = w2K4[j4*64 + lane];
      k0 += rdlane(vm, 4*j4  )*wv.x;
      k1 += rdlane(vm, 4*j4+1)*wv.y;
      k2 += rdlane(vm, 4*j4+2)*wv.z;
      k3 += rdlane(vm, 4*j4+3)*wv.w;
    }
    float K = (k0+k1)+(k2+k3);
    if (c_){
      K2buf[(size_t)fvc*64 + lane] = K;
      float e2   = g2pos ? amx2 : amn2;
      float ext3 = g3pos ? amx3 : amn3;
      VL[(size_t)fvc*64 + lane] =
        make_uint2((unsigned)f2bf(e2) | ((unsigned)f2bf(ext3) << 16), __float_as_uint(sa3));
    }
    S  += (float)PMAX*K + sa;
    Q  += (float)PMAX*K*K + sq + 2.f*K*sa;
    S3 += sa3;
    Q3 += sq3;
  }
  atomicAdd(&sred[lane], S); atomicAdd(&sred[64+lane], Q);
  atomicAdd(&sred[128+lane], S3); atomicAdd(&sred[192+lane], Q3);
  __syncthreads();
  if (tid < 128) atomicAdd(&st2[(blockIdx.x&(SHAD-1))*128 + tid], sred[tid]);
  else           atomicAdd(&st3[(blockIdx.x&(SHAD-1))*128 + (tid-128)], sred[tid]);
}

// p3: loop-free per voxel — vm closed-form, K3 dot, scatter
extern "C" __global__ void __launch_bounds__(256) k_p3(const int* __restrict__ cnt,
    const int* __restrict__ vv, const float* __restrict__ g2, const float* __restrict__ b2,
    const float* __restrict__ w3, const float* __restrict__ g3,
    const float* __restrict__ st2, float* __restrict__ st3,
    const float* __restrict__ K2buf, const uint2* __restrict__ VL,
    unsigned* __restrict__ bev){
  __shared__ float w3KL[4096];    // float4 [j4(16)][lane]
  __shared__ float sred[128];
  int tid = threadIdx.x;
  for (int i = tid; i < 1024; i += 256){
    int j4 = i >> 6, ln = i & 63;
    float4 v;
    v.x = w3[(7+j4*4+0)*64+ln];
    v.y = w3[(7+j4*4+1)*64+ln];
    v.z = w3[(7+j4*4+2)*64+ln];
    v.w = w3[(7+j4*4+3)*64+ln];
    ((float4*)w3KL)[i] = v;
  }
  if (tid < 128) sred[tid] = 0.f;
  int w = tid>>6, lane = tid&63;
  const float invN = 1.f/(float)NPFN;
  float m2=0.f, v2s=0.f;
  #pragma unroll
  for (int s=0;s<SHAD;s++){ m2 += st2[s*128+lane]; v2s += st2[s*128+64+lane]; }
  m2 *= invN; v2s = v2s*invN - m2*m2;
  float sc2 = g2[lane]*rsqrtf(v2s + 1e-3f);
  float sh2 = b2[lane] - m2*sc2;
  bool pickmax = (g3[lane] >= 0.f);
  __syncthreads();
  const float4* w3K4 = (const float4*)w3KL;
  const int wid = blockIdx.x*4 + w;
  int fv = wid*VPW;
  const int lim = min(fv + VPW, NVOX);
  int c_n = 0, vv_n = 0; float K2_n = 0.f;
  uint2 vl_n = make_uint2(0u,0u);
  if (fv < lim){
    c_n  = cnt[fv];
    vv_n = vv[fv];
    K2_n = K2buf[(size_t)fv*64 + lane];
    vl_n = VL[(size_t)fv*64 + lane];
  }
  float S = 0.f, Q = 0.f;
  while (fv < lim){
    const int fvc = fv;
    const int c_ = c_n, vid = vv_n;
    const float K2 = K2_n;
    const uint2 vl = vl_n;
    fv += 1;
    if (fv < lim){
      c_n  = cnt[fv];
      vv_n = vv[fv];
      K2_n = K2buf[(size_t)fv*64 + lane];
      vl_n = VL[(size_t)fv*64 + lane];
    }
    float e2   = bf2f((unsigned short)(vl.x & 0xffffu));
    float ext3 = bf2f((unsigned short)(vl.x >> 16));
    float sa3  = __uint_as_float(vl.y);
    float vm = (c_ > 0) ? fmaxf(0.f, (e2 + K2)*sc2 + sh2) : 0.f;
    float k0=0.f,k1=0.f,k2=0.f,k3=0.f;
    #pragma unroll
    for (int j4=0;j4<16;j4++){
      float4 wv = w3K4[j4*64 + lane];
      k0 += rdlane(vm, 4*j4  )*wv.x;
      k1 += rdlane(vm, 4*j4+1)*wv.y;
      k2 += rdlane(vm, 4*j4+2)*wv.z;
      k3 += rdlane(vm, 4*j4+3)*wv.w;
    }
    float K3 = (k0+k1)+(k2+k3);
    if (c_){
      float raw = ext3 + K3;
      if (!pickmax) raw = -raw;
      unsigned u = __float_as_uint(raw);
      unsigned key = (u & 0x80000000u) ? ~u : (u | 0x80000000u);
      int bb = fvc / MAXV;
      int cx = vid / (GNY*GNZ);
      int cy = (vid / GNZ) % GNY;
      atomicMax(bev + (((size_t)bb*NPIX + (size_t)cy*CONVW + cx)*64) + lane,
                key - KNEGINF);
    }
    S += (float)PMAX*K3;
    Q += (float)PMAX*K3*K3 + (c_ ? 2.f*K3*sa3 : 0.f);
  }
  atomicAdd(&sred[lane], S); atomicAdd(&sred[64+lane], Q);
  __syncthreads();
  if (tid < 128) atomicAdd(&st3[(blockIdx.x&(SHAD-1))*128 + tid], sred[tid]);
}

// ---- conv3x3: implicit GEMM, bf16 MFMA, tile 16x20 (exact fit, no y-guard)
#define CTH 20
extern "C" __global__ void __launch_bounds__(256) k_conv(const unsigned* __restrict__ inK,
    const unsigned short* __restrict__ inH,
    const float* __restrict__ stin, const float* __restrict__ g, const float* __restrict__ be,
    float eps, float invN, int raw0,
    const unsigned short* __restrict__ Bw, const float* __restrict__ bias,
    unsigned short* __restrict__ out, float* __restrict__ st){
  const int b  = blockIdx.z;
  const int x0 = blockIdx.x*16, y0 = blockIdx.y*CTH;
  const int tid = threadIdx.x;
  const int w = tid >> 6, l = tid & 63;
  const int l15 = l & 15, quad = l >> 4;
  const int bid = (blockIdx.z*gridDim.y + blockIdx.y)*gridDim.x + blockIdx.x;
  const int shad = bid & (SHAD-1);

  __shared__ unsigned short smemA[(CTH+2)*18*64];   // 50688 B
  __shared__ float bnsc[64], bnsh[64];
  __shared__ float sA[64], sQ[64];
  if (tid < 64){
    sA[tid] = 0.f; sQ[tid] = 0.f;
    float m = 0.f, q = 0.f;
    #pragma unroll
    for (int s=0;s<SHAD;s++){ m += stin[s*128+tid]; q += stin[s*128+64+tid]; }
    m *= invN;
    float va = q*invN - m*m;
    float sc = g[tid]*rsqrtf(va + eps);
    bnsc[tid] = sc; bnsh[tid] = be[tid] - m*sc;
  }
  __syncthreads();

  for (int i = tid; i < (CTH+2)*18*8; i += 256){
    int pos = i >> 3, jb = i & 7;
    int yp = pos/18, xp = pos - yp*18;
    int gy = y0 + yp - 1, gx = x0 + xp - 1;
    unsigned short h[8] = {0,0,0,0,0,0,0,0};
    if (gy >= 0 && gy < CONVH && gx >= 0 && gx < CONVW){
      size_t ebase = ((size_t)b*NPIX + (size_t)gy*CONVW + gx)*64 + jb*8;
      float f[8];
      if (raw0){
        uint4 u0 = *(const uint4*)(inK + ebase);
        uint4 u1 = *(const uint4*)(inK + ebase + 4);
        unsigned kk[8] = {u0.x,u0.y,u0.z,u0.w,u1.x,u1.y,u1.z,u1.w};
        #pragma unroll
        for (int k=0;k<8;k++){
          unsigned key = kk[k] + KNEGINF;
          unsigned u = (key & 0x80000000u) ? (key & 0x7fffffffu) : ~key;
          float v = __uint_as_float(u);
          int c = jb*8 + k;
          if (bnsc[c] < 0.f) v = -v;
          f[k] = v;
        }
      } else {
        uint4 v4 = *(const uint4*)(inH + ebase);
        unsigned uu[4] = {v4.x, v4.y, v4.z, v4.w};
        #pragma unroll
        for (int e=0;e<4;e++){
          f[e*2]   = bf2f((unsigned short)(uu[e] & 0xffffu));
          f[e*2+1] = bf2f((unsigned short)(uu[e] >> 16));
        }
      }
      #pragma unroll
      for (int k=0;k<8;k++){
        int c = jb*8 + k;
        h[k] = f2bf(fmaxf(f[k]*bnsc[c] + bnsh[c], 0.f));
      }
    }
    int jsw = jb ^ (xp & 7);
    *(uint4*)&smemA[pos*64 + jsw*8] = *(uint4*)h;
  }
  __syncthreads();

  f32x4 acc[5][4];
  #pragma unroll
  for (int rr=0;rr<5;rr++)
    #pragma unroll
    for (int nt=0;nt<4;nt++) acc[rr][nt] = (f32x4){0.f,0.f,0.f,0.f};
  #pragma unroll
  for (int tap = 0; tap < 9; tap++){
    const int dy = tap/3, dx = tap - dy*3;
    const int xp = l15 + dx;
    const int xm = xp & 7;
    short8 b0[4], b1[4];
    #pragma unroll
    for (int nt = 0; nt < 4; nt++){
      const unsigned short* bp = Bw + (((size_t)tap*64 + nt*16 + l15)*64 + quad*8);
      b0[nt] = *(const short8*)bp;
      b1[nt] = *(const short8*)(bp + 32);
    }
    #pragma unroll
    for (int rr = 0; rr < 5; rr++){
      int yp = 5*w + rr + dy;
      int abase = (yp*18 + xp)*64;
      short8 aL = *(const short8*)&smemA[abase + ((quad    ) ^ xm)*8];
      short8 aH = *(const short8*)&smemA[abase + ((4 + quad) ^ xm)*8];
      #pragma unroll
      for (int nt = 0; nt < 4; nt++)
        acc[rr][nt] = __builtin_amdgcn_mfma_f32_16x16x32_bf16(aL, b0[nt], acc[rr][nt], 0,0,0);
      #pragma unroll
      for (int nt = 0; nt < 4; nt++)
        acc[rr][nt] = __builtin_amdgcn_mfma_f32_16x16x32_bf16(aH, b1[nt], acc[rr][nt], 0,0,0);
    }
  }

  #pragma unroll
  for (int nt = 0; nt < 4; nt++){
    int oc = nt*16 + l15;
    float bv = bias[oc];
    float s = 0.f, q = 0.f;
    #pragma unroll
    for (int rr = 0; rr < 5; rr++){
      int y = y0 + 5*w + rr;
      size_t rbase = ((size_t)b*NPIX + (size_t)y*CONVW)*64;
      #pragma unroll
      for (int r = 0; r < 4; r++){
        float v = acc[rr][nt][r] + bv;
        int x = x0 + quad*4 + r;
        out[rbase + (size_t)x*64 + oc] = f2bf(v);
        s += v; q += v*v;
      }
    }
    s += __shfl_xor(s, 16); s += __shfl_xor(s, 32);
    q += __shfl_xor(q, 16); q += __shfl_xor(q, 32);
    if (quad == 0){ atomicAdd(&sA[oc], s); atomicAdd(&sQ[oc], q); }
  }
  __syncthreads();
  if (tid < 64){
    atomicAdd(&st[shad*128 + tid], sA[tid]);
    atomicAdd(&st[shad*128 + 64 + tid], sQ[tid]);
  }
}

// ---- head 1x1: bf16 in + fused BN/relu of last conv layer
extern "C" __global__ void __launch_bounds__(256) k_head(const unsigned short* __restrict__ in,
    const float* __restrict__ stin, const float* __restrict__ g, const float* __restrict__ be,
    const float* __restrict__ hw, const float* __restrict__ hb, float* __restrict__ outp){
  __shared__ float bnsc[64], bnsh[64];
  int tid = threadIdx.x;
  if (tid < 64){
    const float invN = 1.f/(float)(BATCH*NPIX);
    float m = 0.f, q = 0.f;
    #pragma unroll
    for (int s=0;s<SHAD;s++){ m += stin[s*128+tid]; q += stin[s*128+64+tid]; }
    m *= invN;
    float va = q*invN - m*m;
    float sc = g[tid]*rsqrtf(va + 1e-5f);
    bnsc[tid] = sc; bnsh[tid] = be[tid] - m*sc;
  }
  __syncthreads();
  int i = blockIdx.x*256 + tid;
  if (i >= BATCH*NPIX) return;
  const uint4* p = (const uint4*)(in + (size_t)i*64);
  float a0 = hb[0], a1 = hb[1], a2 = hb[2];
  #pragma unroll
  for (int jb = 0; jb < 8; jb++){
    uint4 u = p[jb];
    unsigned uu[4] = {u.x, u.y, u.z, u.w};
    #pragma unroll
    for (int e = 0; e < 4; e++){
      int ic = jb*8 + e*2;
      float v0 = bf2f((unsigned short)(uu[e] & 0xffffu));
      float v1 = bf2f((unsigned short)(uu[e] >> 16));
      float h0 = fmaxf(v0*bnsc[ic]   + bnsh[ic],   0.f);
      float h1 = fmaxf(v1*bnsc[ic+1] + bnsh[ic+1], 0.f);
      a0 += h0*hw[ic] + h1*hw[ic+1];
      a1 += h0*hw[64+ic] + h1*hw[64+ic+1];
      a2 += h0*hw[128+ic] + h1*hw[128+ic+1];
    }
  }
  size_t o = (size_t)i*3;
  outp[o+0] = a0; outp[o+1] = a1; outp[o+2] = a2;
}

extern "C" void kernel_launch(void* const* d_in, const int* in_sizes, int n_in,
                              void* d_out, int out_size, void* d_ws, size_t ws_size,
                              hipStream_t stream){
  (void)in_sizes; (void)n_in; (void)out_size;
  const float* pts   = (const float*)d_in[0];
  const float* w1    = (const float*)d_in[1];
  const float* g1    = (const float*)d_in[2];
  const float* b1    = (const float*)d_in[3];
  const float* w2    = (const float*)d_in[4];
  const float* g2    = (const float*)d_in[5];
  const float* b2    = (const float*)d_in[6];
  const float* w3    = (const float*)d_in[7];
  const float* g3    = (const float*)d_in[8];
  const float* b3    = (const float*)d_in[9];
  const float* cs_w  = (const float*)d_in[10];
  const float* cs_b  = (const float*)d_in[11];
  const float* cs_g  = (const float*)d_in[12];
  const float* cs_be = (const float*)d_in[13];
  const float* rpn_w = (const float*)d_in[14];
  const float* rpn_b = (const float*)d_in[15];
  const float* rpn_g = (const float*)d_in[16];
  const float* rpn_be= (const float*)d_in[17];
  const float* hw    = (const float*)d_in[18];
  const float* hb    = (const float*)d_in[19];

  char* ws = (char*)d_ws;
  size_t off = 0;
  auto alloc = [&](size_t bytes)->char*{
    char* p = ws + off; off += (bytes + 255) & ~(size_t)255; return p;
  };
  // ---- zero region (k_init) ----
  int*   cellcnt = (int*)  alloc((size_t)BATCH*NCELL*4);
  int*   vv      = (int*)  alloc((size_t)NVOX*4);
  int*   cnt     = (int*)  alloc((size_t)NVOX*4);
  int*   fill    = (int*)  alloc((size_t)NVOX*4);
  float* stats   = (float*)alloc(131072);
  unsigned* bevk = (unsigned*)alloc((size_t)NELEM*4);       // biased keys: 0 == -inf
  size_t zbytes  = off;
  // ---- no-init region ----
  int*   slotmap = (int*)  alloc((size_t)BATCH*NCELL*4);
  int*   blks    = (int*)  alloc((size_t)BATCH*512*4);
  int*   plist   = (int*)  alloc((size_t)NVOX*PMAX*4);      // conv alias start
  float* pvox    = (float*)alloc((size_t)NVOX*PMAX*16);
  float* mean    = (float*)alloc((size_t)NVOX*16);
  float* K2buf   = (float*)alloc((size_t)NVOX*64*4);
  uint2* VLbuf   = (uint2*)alloc((size_t)NVOX*64*8);
  unsigned short* Bw = (unsigned short*)alloc((size_t)5*36864*2);
  if (off > ws_size) return;

  float* st1 = stats;            // [8][64]
  float* st2 = stats + 512;      // [8][128]
  float* st3 = stats + 1536;     // [8][128]
  float* stc = stats + 2560;     // 5 x [8][128]

  unsigned short* convA = (unsigned short*)plist;
  unsigned short* convB = (unsigned short*)((char*)plist + 9011200);

  k_init<<<2048, 256, 0, stream>>>(cs_w, rpn_w, Bw, (uint4*)ws, (int)(zbytes/16));

  k_count <<<(BATCH*NPTS/2+255)/256, 256, 0, stream>>>(pts, cellcnt);
  k_blkcount<<<dim3(SCAN_NB,BATCH), 256, 0, stream>>>(cellcnt, blks);
  k_assign<<<dim3(SCAN_NB,BATCH), 256, 0, stream>>>(cellcnt, blks, slotmap, vv, cnt);
  k_fill  <<<(BATCH*NPTS/2+255)/256, 256, 0, stream>>>(pts, slotmap, fill, plist);
  k_feat  <<<NVOX/32, 256, 0, stream>>>(pts, cnt, plist, w1, pvox, mean, st1);

  k_p2<<<PGRID, 256, 0, stream>>>(pvox, mean, cnt, w1, g1, b1, w2, w3, g2, g3,
                                  st1, st2, st3, K2buf, VLbuf);
  k_p3<<<PGRID, 256, 0, stream>>>(cnt, vv, g2, b2, w3, g3, st2, st3,
                                  K2buf, VLbuf, bevk);

  const float* bptr[5]  = {cs_b, cs_b+64,   rpn_b, rpn_b+64,   rpn_b+128};
  const float* gptr[5]  = {cs_g, cs_g+64,   rpn_g, rpn_g+64,   rpn_g+128};
  const float* beptr[5] = {cs_be,cs_be+64,  rpn_be,rpn_be+64,  rpn_be+128};
  const unsigned short* srcs[5] = {nullptr, convA, convB, convA, convB};
  unsigned short*       dsts[5] = {convA, convB, convA, convB, convA};
  dim3 cgrid(CONVW/16, CONVH/CTH, BATCH);
  for (int ll = 0; ll < 5; ll++){
    const float* stin = (ll == 0) ? st3 : (stc + (ll-1)*1024);
    const float* gg   = (ll == 0) ? g3 : gptr[ll-1];
    const float* bb   = (ll == 0) ? b3 : beptr[ll-1];
    float eps  = (ll == 0) ? 1e-3f : 1e-5f;
    float invN = (ll == 0) ? 1.f/(float)NPFN : 1.f/(float)(BATCH*NPIX);
    k_conv<<<cgrid, 256, 0, stream>>>((ll==0)?bevk:nullptr, srcs[ll],
                                      stin, gg, bb, eps, invN, (ll==0)?1:0,
                                      Bw + (size_t)ll*36864, bptr[ll], dsts[ll],
                                      stc + ll*1024);
  }
  k_head<<<(BATCH*NPIX+255)/256, 256, 0, stream>>>(convA, stc + 4*1024, gptr[4], beptr[4],
                                                   hw, hb, (float*)d_out);
}